// Round 6
// baseline (363.709 us; speedup 1.0000x reference)
//
#include <hip/hip_runtime.h>
#include <math.h>

// Problem constants
#define T_DIM 1024
#define N_DIM 8192
#define M_TOT (T_DIM * N_DIM)          // 8,388,608
#define NV4   (N_DIM / 4)              // 2048 float4 per row
#define L_CHUNK 8
#define C_CHUNKS (T_DIM / L_CHUNK)     // 128
#define PC_BLOCKS ((C_CHUNKS * NV4) / 256)   // 1024
#define SCAN_BLOCKS ((NV4 * 32) / 256)       // 256  (32 slices x 4 chunks)

#define kGAMMA 0.99f
#define kGLAM  (0.99f * 0.95f)

// ws layout (~42 MB):
//   +0            acc doubles: 1=sum_g 2=sum_g2 3=vsum 5=mu 6=invs 7=asum 8=esum
//   +128          cnt[2] uint   -- last-block-done counters (k_gae, k_loss)
//   +65536        b16 [T][N] ushort (16 MB)   -- bf16 b_t, a-bit in LSB
//   +65536+16MB   q16 [T][N] ushort (16 MB)   -- bf16 (new_value - value_preds)
//   +65536+32MB   A   [C][N] float (4 MB)     -- chunk-map A, overwritten w/ g_in
//   +65536+36MB   B   [C][N] float (4 MB)

__device__ __forceinline__ unsigned short f2bf(float f) {
    unsigned int u = __float_as_uint(f);
    u += 0x7fffu + ((u >> 16) & 1u);        // round-to-nearest-even
    return (unsigned short)(u >> 16);
}
__device__ __forceinline__ float bf2f(unsigned short h) {
    return __uint_as_float(((unsigned int)h) << 16);
}

// ---------------------------------------------------------------------------
// K1: fused prep+chunk (round-2 proven body) + q16 = bf16(nv - vp) store.
// Thread (c, j): row-serial descending-t loop with vnext carry; emits b_t
// (bf16, a-bit in LSB), q16, and the chunk map (A,B). Zeroes acc/counters.
__global__ __launch_bounds__(256) void k_pc(
    const float4* __restrict__ r4,
    const float4* __restrict__ m4,     // (T+1) rows
    const float4* __restrict__ bm4,    // (T+1) rows
    const float4* __restrict__ vp4,    // (T+1) rows
    const float4* __restrict__ lv4,    // (N,)
    const float4* __restrict__ nv4,    // new_value (T,N)
    ushort4* __restrict__ b16,
    ushort4* __restrict__ q16,
    float4* __restrict__ A_out,
    float4* __restrict__ B_out,
    double* __restrict__ acc,
    unsigned int* __restrict__ cnt)
{
    const int g  = blockIdx.x * 256 + threadIdx.x;   // 0 .. C*NV4-1
    if (g == 0) {
        acc[1] = 0.0; acc[2] = 0.0; acc[3] = 0.0; acc[7] = 0.0; acc[8] = 0.0;
        cnt[0] = 0u; cnt[1] = 0u;
    }
    const int j  = g & (NV4 - 1);
    const int c  = g >> 11;
    const int t0 = c * L_CHUNK;

    float4 vnext = (c == C_CHUNKS - 1) ? lv4[j] : vp4[(t0 + L_CHUNK) * NV4 + j];
    float4 Aa = make_float4(1.f, 1.f, 1.f, 1.f);
    float4 Bb = make_float4(0.f, 0.f, 0.f, 0.f);

    #pragma unroll
    for (int i = L_CHUNK - 1; i >= 0; --i) {
        const int idx = (t0 + i) * NV4 + j;
        const float4 r  = r4[idx];
        const float4 v  = vp4[idx];
        const float4 nv = nv4[idx];
        const float4 m  = m4[idx + NV4];             // row t+1
        const float4 bb = bm4[idx + NV4];            // row t+1

        ushort4 o, qo;
#define P1C(comp) { \
        const float b = (fmaf(kGAMMA * m.comp, vnext.comp, r.comp) - v.comp) * bb.comp; \
        const float a = kGLAM * m.comp * bb.comp; \
        Aa.comp = a * Aa.comp; Bb.comp = fmaf(a, Bb.comp, b); \
        o.comp  = (unsigned short)((f2bf(b) & 0xFFFEu) | ((m.comp * bb.comp > 0.5f) ? 1u : 0u)); \
        qo.comp = f2bf(nv.comp - v.comp); }
        P1C(x) P1C(y) P1C(z) P1C(w)
#undef P1C
        b16[idx] = o;
        q16[idx] = qo;
        vnext = v;
    }
    A_out[c * NV4 + j] = Aa;
    B_out[c * NV4 + j] = Bb;
}

// ---------------------------------------------------------------------------
// K2: parallel suffix scan of the 128 affine chunk maps (verified bit-exact
// since round 3 — body unchanged). Thread (jj, k): slice k = chunks 4k..4k+3;
// 32-lane shuffle groups share one jj. g_in overwrites Ag.
__global__ __launch_bounds__(256, 8) void k_scan(
    float4* __restrict__ Ag,           // in: A, out: g_in
    const float4* __restrict__ Bg)
{
    const int u  = blockIdx.x * 256 + threadIdx.x;   // 0 .. NV4*32-1
    const int jj = u >> 5;
    const int k  = u & 31;

    float4 As[4], Bs[4];
    #pragma unroll
    for (int i = 0; i < 4; ++i) {
        As[i] = Ag[(4 * k + i) * NV4 + jj];
        Bs[i] = Bg[(4 * k + i) * NV4 + jj];
    }
    // slice map M_k = f_{4k} o ... o f_{4k+3} (highest chunk applied first)
    float4 Pa = As[3], Pb = Bs[3];
    #pragma unroll
    for (int i = 2; i >= 0; --i) {
        Pb.x = fmaf(As[i].x, Pb.x, Bs[i].x); Pa.x = As[i].x * Pa.x;
        Pb.y = fmaf(As[i].y, Pb.y, Bs[i].y); Pa.y = As[i].y * Pa.y;
        Pb.z = fmaf(As[i].z, Pb.z, Bs[i].z); Pa.z = As[i].z * Pa.z;
        Pb.w = fmaf(As[i].w, Pb.w, Bs[i].w); Pa.w = As[i].w * Pa.w;
    }
    // inclusive suffix scan across 32 slices
    #pragma unroll
    for (int d = 1; d < 32; d <<= 1) {
        const float nax = __shfl_down(Pa.x, d, 32), nay = __shfl_down(Pa.y, d, 32);
        const float naz = __shfl_down(Pa.z, d, 32), naw = __shfl_down(Pa.w, d, 32);
        const float nbx = __shfl_down(Pb.x, d, 32), nby = __shfl_down(Pb.y, d, 32);
        const float nbz = __shfl_down(Pb.z, d, 32), nbw = __shfl_down(Pb.w, d, 32);
        if (k + d < 32) {               // compose: current o neighbor
            Pb.x = fmaf(Pa.x, nbx, Pb.x); Pa.x *= nax;
            Pb.y = fmaf(Pa.y, nby, Pb.y); Pa.y *= nay;
            Pb.z = fmaf(Pa.z, nbz, Pb.z); Pa.z *= naz;
            Pb.w = fmaf(Pa.w, nbw, Pb.w); Pa.w *= naw;
        }
    }
    // incoming gae for slice k = P_{k+1}(0) = B of lane k+1 (0 for k==31)
    float4 G;
    G.x = __shfl_down(Pb.x, 1, 32);
    G.y = __shfl_down(Pb.y, 1, 32);
    G.z = __shfl_down(Pb.z, 1, 32);
    G.w = __shfl_down(Pb.w, 1, 32);
    if (k == 31) G = make_float4(0.f, 0.f, 0.f, 0.f);
    // back-fill per-chunk incoming gae (highest chunk of slice first)
    #pragma unroll
    for (int i = 3; i >= 0; --i) {
        Ag[(4 * k + i) * NV4 + jj] = G;
        G.x = fmaf(As[i].x, G.x, Bs[i].x);
        G.y = fmaf(As[i].y, G.y, Bs[i].y);
        G.z = fmaf(As[i].z, G.z, Bs[i].z);
        G.w = fmaf(As[i].w, G.w, Bs[i].w);
    }
}

// ---------------------------------------------------------------------------
// K3: gae + stats + value loss from b16 + q16 + g_in ONLY (36 MB total).
// Block partials -> f64 atomics into acc; last-finishing block computes
// mu / inv(std+eps) into acc (fence+counter, dispatch-order independent).
__global__ __launch_bounds__(256) void k_gae(
    const ushort4* __restrict__ b16,
    const ushort4* __restrict__ q16,
    const float4* __restrict__ g_in4,
    double* __restrict__ acc,
    unsigned int* __restrict__ cnt)
{
    const int g  = blockIdx.x * 256 + threadIdx.x;
    const int j  = g & (NV4 - 1);
    const int c  = g >> 11;
    const int t0 = c * L_CHUNK;

    float4 gae = g_in4[c * NV4 + j];
    float sg = 0.f, sg2 = 0.f, v_s = 0.f;

    #pragma unroll
    for (int i = L_CHUNK - 1; i >= 0; --i) {
        const int idx = (t0 + i) * NV4 + j;
        const ushort4 h = b16[idx];
        const ushort4 qh = q16[idx];
#define P3C(comp, HH, QH) { \
        const unsigned short hh = (HH); \
        const float bf = bf2f(hh); \
        const float a  = (hh & 1u) ? kGLAM : 0.0f; \
        gae.comp = fmaf(a, gae.comp, bf); \
        sg += gae.comp; sg2 = fmaf(gae.comp, gae.comp, sg2); \
        const float qd = bf2f(QH); \
        const float e1 = qd - gae.comp; \
        const float e2 = fminf(fmaxf(qd, -0.2f), 0.2f) - gae.comp; \
        v_s += fmaxf(e1 * e1, e2 * e2); }
        P3C(x, h.x, qh.x) P3C(y, h.y, qh.y) P3C(z, h.z, qh.z) P3C(w, h.w, qh.w)
#undef P3C
    }

    double d0 = (double)sg, d1 = (double)sg2, d2 = (double)v_s;
    #pragma unroll
    for (int off = 32; off > 0; off >>= 1) {
        d0 += __shfl_down(d0, off, 64);
        d1 += __shfl_down(d1, off, 64);
        d2 += __shfl_down(d2, off, 64);
    }
    __shared__ double sh[3][4];
    const int wid = threadIdx.x >> 6, lane = threadIdx.x & 63;
    if (lane == 0) { sh[0][wid] = d0; sh[1][wid] = d1; sh[2][wid] = d2; }
    __syncthreads();
    if (threadIdx.x == 0) {
        double t0s = 0, t1s = 0, t2s = 0;
        #pragma unroll
        for (int w = 0; w < 4; ++w) { t0s += sh[0][w]; t1s += sh[1][w]; t2s += sh[2][w]; }
        atomicAdd(&acc[1], t0s);
        atomicAdd(&acc[2], t1s);
        atomicAdd(&acc[3], t2s);
        __threadfence();
        const unsigned int old = atomicAdd(&cnt[0], 1u);
        if (old == (unsigned int)(PC_BLOCKS - 1)) {   // last block done
            __threadfence();
            const double M = (double)M_TOT;
            const double sum = acc[1], sum2 = acc[2];
            const double mu = sum / M;
            double var = (sum2 - sum * sum / M) / (M - 1.0);
            if (var < 0.0) var = 0.0;
            acc[5] = mu;
            acc[6] = 1.0 / (sqrt(var) + 1e-5);
        }
    }
}

// ---------------------------------------------------------------------------
// K4: action loss + entropy (round-5 proven body). mu/invs from acc.
// Block partials -> f64 atomics; last-finishing block emits the final scalar.
__global__ __launch_bounds__(256, 4) void k_loss(
    const ushort4* __restrict__ b16,
    const float4* __restrict__ g_in4,
    const float4* __restrict__ lp4,
    const float4* __restrict__ plp4,
    const float4* __restrict__ ent4,
    double* __restrict__ acc,
    unsigned int* __restrict__ cnt,
    float* __restrict__ out)
{
    const int tid = threadIdx.x;
    const int g  = blockIdx.x * 256 + tid;
    const int j  = g & (NV4 - 1);
    const int c  = g >> 11;
    const int t0 = c * L_CHUNK;

    const float mu   = (float)acc[5];
    const float invs = (float)acc[6];

    float4 gv = g_in4[c * NV4 + j];
    float a_s = 0.f, e_s = 0.f;

    #pragma unroll
    for (int half = 0; half < 2; ++half) {
        const int ibase = (half == 0) ? 7 : 3;       // i = ibase-u, u=0..3
        ushort4 H[4]; float4 L[4], P[4], E[4];
        #pragma unroll
        for (int u = 0; u < 4; ++u) {
            const int idx = (t0 + ibase - u) * NV4 + j;
            H[u] = b16[idx];
            L[u] = lp4[idx];
            P[u] = plp4[idx];
            E[u] = ent4[idx];
        }
        #pragma unroll
        for (int u = 0; u < 4; ++u) {
#define P5C(comp, HH) { \
            const unsigned short hh = (HH); \
            const float bf = bf2f(hh); \
            const float a  = (hh & 1u) ? kGLAM : 0.0f; \
            gv.comp = fmaf(a, gv.comp, bf); \
            const float x  = (gv.comp - mu) * invs; \
            const float rr = __expf(L[u].comp - P[u].comp); \
            const float rc = fminf(fmaxf(rr, 0.8f), 1.2f); \
            a_s += fminf(rr * x, rc * x); }
            P5C(x, H[u].x) P5C(y, H[u].y) P5C(z, H[u].z) P5C(w, H[u].w)
#undef P5C
            e_s += E[u].x + E[u].y + E[u].z + E[u].w;
        }
    }

    double d0 = (double)a_s, d1 = (double)e_s;
    #pragma unroll
    for (int off = 32; off > 0; off >>= 1) {
        d0 += __shfl_down(d0, off, 64);
        d1 += __shfl_down(d1, off, 64);
    }
    __shared__ double sh[2][4];
    const int wid = tid >> 6, lane = tid & 63;
    if (lane == 0) { sh[0][wid] = d0; sh[1][wid] = d1; }
    __syncthreads();
    if (tid == 0) {
        double t0s = 0, t1s = 0;
        #pragma unroll
        for (int w = 0; w < 4; ++w) { t0s += sh[0][w]; t1s += sh[1][w]; }
        atomicAdd(&acc[7], t0s);
        atomicAdd(&acc[8], t1s);
        __threadfence();
        const unsigned int old = atomicAdd(&cnt[1], 1u);
        if (old == (unsigned int)(PC_BLOCKS - 1)) {   // last block done
            __threadfence();
            const double M = (double)M_TOT;
            out[0] = (float)(0.25 * acc[3] / M - acc[7] / M - 0.01 * acc[8] / M);
        }
    }
}

// ---------------------------------------------------------------------------
extern "C" void kernel_launch(void* const* d_in, const int* in_sizes, int n_in,
                              void* d_out, int out_size, void* d_ws, size_t ws_size,
                              hipStream_t stream) {
    const float* rewards     = (const float*)d_in[0];   // (T, N)
    const float* masks       = (const float*)d_in[1];   // (T+1, N)
    const float* bad_masks   = (const float*)d_in[2];   // (T+1, N)
    const float* value_preds = (const float*)d_in[3];   // (T+1, N)
    const float* last_value  = (const float*)d_in[4];   // (N,)
    const float* log_prob    = (const float*)d_in[5];   // (T, N)
    const float* prev_lp     = (const float*)d_in[6];   // (T, N)
    const float* new_value   = (const float*)d_in[7];   // (T, N)
    const float* dist_ent    = (const float*)d_in[8];   // (T, N)

    char* ws = (char*)d_ws;
    double* acc = (double*)ws;
    unsigned int* cnt = (unsigned int*)(ws + 128);
    unsigned short* b16 = (unsigned short*)(ws + 65536);
    unsigned short* q16 = (unsigned short*)(ws + 65536 + (size_t)M_TOT * 2);
    float* A = (float*)(ws + 65536 + (size_t)M_TOT * 4);
    float* B = (float*)(ws + 65536 + (size_t)M_TOT * 4 + (size_t)C_CHUNKS * N_DIM * 4);

    k_pc<<<PC_BLOCKS, 256, 0, stream>>>((const float4*)rewards,
                                        (const float4*)masks,
                                        (const float4*)bad_masks,
                                        (const float4*)value_preds,
                                        (const float4*)last_value,
                                        (const float4*)new_value,
                                        (ushort4*)b16, (ushort4*)q16,
                                        (float4*)A, (float4*)B, acc, cnt);
    k_scan<<<SCAN_BLOCKS, 256, 0, stream>>>((float4*)A, (const float4*)B);
    k_gae<<<PC_BLOCKS, 256, 0, stream>>>((const ushort4*)b16,
                                         (const ushort4*)q16,
                                         (const float4*)A /* g_in */,
                                         acc, cnt);
    k_loss<<<PC_BLOCKS, 256, 0, stream>>>((const ushort4*)b16,
                                          (const float4*)A /* g_in */,
                                          (const float4*)log_prob,
                                          (const float4*)prev_lp,
                                          (const float4*)dist_ent,
                                          acc, cnt, (float*)d_out);
}

// Round 7
// 275.122 us; speedup vs baseline: 1.3220x; 1.3220x over previous
//
#include <hip/hip_runtime.h>
#include <math.h>

// Problem constants
#define T_DIM 1024
#define N_DIM 8192
#define M_TOT (T_DIM * N_DIM)          // 8,388,608
#define NV4   (N_DIM / 4)              // 2048 float4 per row
#define L_CHUNK 8
#define C_CHUNKS (T_DIM / L_CHUNK)     // 128
#define PC_BLOCKS ((C_CHUNKS * NV4) / 256)   // 1024
#define SCAN_BLOCKS ((NV4 * 32) / 256)       // 256  (32 slices x 4 chunks)

#define kGAMMA 0.99f
#define kGLAM  (0.99f * 0.95f)

// ws layout (~44.1 MB):
//   +256          ps [1024][2] doubles (16 KB) -- k_cs block partials (sum, sum2)
//   +32768        pl [1024][3] doubles (24 KB) -- k_fused partials (vsum, asum, esum)
//   +65536        b16 [T][N] ushort (16 MB)    -- bf16 b_t, a-bit in LSB
//   +65536+16MB   A [C][N] float (4 MB)        -- chunk-map A, overwritten w/ g_in
//   +65536+20MB   B [C][N] float (4 MB)
//   +65536+24MB   P,Q,U,V,W [C][N] float (5 x 4 MB) -- chunk moment coefficients:
//                 per chunk, Σgae = P*g_in + Q ; Σgae² = U*g_in² + 2V*g_in + W

__device__ __forceinline__ unsigned short f2bf(float f) {
    unsigned int u = __float_as_uint(f);
    u += 0x7fffu + ((u >> 16) & 1u);        // round-to-nearest-even
    return (unsigned short)(u >> 16);
}
__device__ __forceinline__ float bf2f(unsigned short h) {
    return __uint_as_float(((unsigned int)h) << 16);
}

// ---------------------------------------------------------------------------
// K1: fused prep+chunk (round-2/5 proven body) + chunk moment coefficients.
// After each row's (Aa,Bb) update, (Aa,Bb) = (alpha_t, beta_t) of that row:
// gae_t = alpha_t * g_in + beta_t. Accumulate P,Q,U,V,W.
__global__ __launch_bounds__(256) void k_pc(
    const float4* __restrict__ r4,
    const float4* __restrict__ m4,     // (T+1) rows
    const float4* __restrict__ bm4,    // (T+1) rows
    const float4* __restrict__ vp4,    // (T+1) rows
    const float4* __restrict__ lv4,    // (N,)
    ushort4* __restrict__ b16,
    float4* __restrict__ A_out,
    float4* __restrict__ B_out,
    float4* __restrict__ P_out,
    float4* __restrict__ Q_out,
    float4* __restrict__ U_out,
    float4* __restrict__ V_out,
    float4* __restrict__ W_out)
{
    const int g  = blockIdx.x * 256 + threadIdx.x;   // 0 .. C*NV4-1
    const int j  = g & (NV4 - 1);
    const int c  = g >> 11;
    const int t0 = c * L_CHUNK;

    float4 vnext = (c == C_CHUNKS - 1) ? lv4[j] : vp4[(t0 + L_CHUNK) * NV4 + j];
    float4 Aa = make_float4(1.f, 1.f, 1.f, 1.f);
    float4 Bb = make_float4(0.f, 0.f, 0.f, 0.f);
    float4 Ps = make_float4(0.f, 0.f, 0.f, 0.f);
    float4 Qs = make_float4(0.f, 0.f, 0.f, 0.f);
    float4 Us = make_float4(0.f, 0.f, 0.f, 0.f);
    float4 Vs = make_float4(0.f, 0.f, 0.f, 0.f);
    float4 Ws = make_float4(0.f, 0.f, 0.f, 0.f);

    #pragma unroll
    for (int i = L_CHUNK - 1; i >= 0; --i) {
        const int idx = (t0 + i) * NV4 + j;
        const float4 r  = r4[idx];
        const float4 v  = vp4[idx];
        const float4 m  = m4[idx + NV4];             // row t+1
        const float4 bb = bm4[idx + NV4];            // row t+1

        ushort4 o;
#define P1C(comp) { \
        const float b = (fmaf(kGAMMA * m.comp, vnext.comp, r.comp) - v.comp) * bb.comp; \
        const float a = kGLAM * m.comp * bb.comp; \
        Aa.comp = a * Aa.comp; Bb.comp = fmaf(a, Bb.comp, b); \
        Ps.comp += Aa.comp; Qs.comp += Bb.comp; \
        Us.comp = fmaf(Aa.comp, Aa.comp, Us.comp); \
        Vs.comp = fmaf(Aa.comp, Bb.comp, Vs.comp); \
        Ws.comp = fmaf(Bb.comp, Bb.comp, Ws.comp); \
        o.comp = (unsigned short)((f2bf(b) & 0xFFFEu) | ((m.comp * bb.comp > 0.5f) ? 1u : 0u)); }
        P1C(x) P1C(y) P1C(z) P1C(w)
#undef P1C
        b16[idx] = o;
        vnext = v;
    }
    const int o = c * NV4 + j;
    A_out[o] = Aa;
    B_out[o] = Bb;
    P_out[o] = Ps;
    Q_out[o] = Qs;
    U_out[o] = Us;
    V_out[o] = Vs;
    W_out[o] = Ws;
}

// ---------------------------------------------------------------------------
// K2: parallel suffix scan of the 128 affine chunk maps (verified bit-exact
// since round 3 — body unchanged). Thread (jj, k): slice k = chunks 4k..4k+3;
// 32-lane shuffle groups share one jj. g_in overwrites Ag.
__global__ __launch_bounds__(256, 8) void k_scan(
    float4* __restrict__ Ag,           // in: A, out: g_in
    const float4* __restrict__ Bg)
{
    const int u  = blockIdx.x * 256 + threadIdx.x;   // 0 .. NV4*32-1
    const int jj = u >> 5;
    const int k  = u & 31;

    float4 As[4], Bs[4];
    #pragma unroll
    for (int i = 0; i < 4; ++i) {
        As[i] = Ag[(4 * k + i) * NV4 + jj];
        Bs[i] = Bg[(4 * k + i) * NV4 + jj];
    }
    // slice map M_k = f_{4k} o ... o f_{4k+3} (highest chunk applied first)
    float4 Pa = As[3], Pb = Bs[3];
    #pragma unroll
    for (int i = 2; i >= 0; --i) {
        Pb.x = fmaf(As[i].x, Pb.x, Bs[i].x); Pa.x = As[i].x * Pa.x;
        Pb.y = fmaf(As[i].y, Pb.y, Bs[i].y); Pa.y = As[i].y * Pa.y;
        Pb.z = fmaf(As[i].z, Pb.z, Bs[i].z); Pa.z = As[i].z * Pa.z;
        Pb.w = fmaf(As[i].w, Pb.w, Bs[i].w); Pa.w = As[i].w * Pa.w;
    }
    // inclusive suffix scan across 32 slices
    #pragma unroll
    for (int d = 1; d < 32; d <<= 1) {
        const float nax = __shfl_down(Pa.x, d, 32), nay = __shfl_down(Pa.y, d, 32);
        const float naz = __shfl_down(Pa.z, d, 32), naw = __shfl_down(Pa.w, d, 32);
        const float nbx = __shfl_down(Pb.x, d, 32), nby = __shfl_down(Pb.y, d, 32);
        const float nbz = __shfl_down(Pb.z, d, 32), nbw = __shfl_down(Pb.w, d, 32);
        if (k + d < 32) {               // compose: current o neighbor
            Pb.x = fmaf(Pa.x, nbx, Pb.x); Pa.x *= nax;
            Pb.y = fmaf(Pa.y, nby, Pb.y); Pa.y *= nay;
            Pb.z = fmaf(Pa.z, nbz, Pb.z); Pa.z *= naz;
            Pb.w = fmaf(Pa.w, nbw, Pb.w); Pa.w *= naw;
        }
    }
    // incoming gae for slice k = P_{k+1}(0) = B of lane k+1 (0 for k==31)
    float4 G;
    G.x = __shfl_down(Pb.x, 1, 32);
    G.y = __shfl_down(Pb.y, 1, 32);
    G.z = __shfl_down(Pb.z, 1, 32);
    G.w = __shfl_down(Pb.w, 1, 32);
    if (k == 31) G = make_float4(0.f, 0.f, 0.f, 0.f);
    // back-fill per-chunk incoming gae (highest chunk of slice first)
    #pragma unroll
    for (int i = 3; i >= 0; --i) {
        Ag[(4 * k + i) * NV4 + jj] = G;
        G.x = fmaf(As[i].x, G.x, Bs[i].x);
        G.y = fmaf(As[i].y, G.y, Bs[i].y);
        G.z = fmaf(As[i].z, G.z, Bs[i].z);
        G.w = fmaf(As[i].w, G.w, Bs[i].w);
    }
}

// ---------------------------------------------------------------------------
// K3: chunk-moment stats — EXACT Σgae and Σgae² from coefficients + g_in,
// no pass over b16 (24 MB total). Block partials -> ps (plain stores).
__global__ __launch_bounds__(256) void k_cs(
    const float4* __restrict__ g_in4,
    const float4* __restrict__ P4,
    const float4* __restrict__ Q4,
    const float4* __restrict__ U4,
    const float4* __restrict__ V4,
    const float4* __restrict__ W4,
    double* __restrict__ ps)           // [PC_BLOCKS][2]
{
    const int g = blockIdx.x * 256 + threadIdx.x;    // 0 .. C*NV4-1
    const float4 gg = g_in4[g];
    const float4 p  = P4[g];
    const float4 q  = Q4[g];
    const float4 uu = U4[g];
    const float4 vv = V4[g];
    const float4 ww = W4[g];

    float s1 = 0.f, s2 = 0.f;
#define CSC(comp) { \
    s1 += fmaf(p.comp, gg.comp, q.comp); \
    s2 += fmaf(fmaf(uu.comp, gg.comp, 2.0f * vv.comp), gg.comp, ww.comp); }
    CSC(x) CSC(y) CSC(z) CSC(w)
#undef CSC

    double d0 = (double)s1, d1 = (double)s2;
    #pragma unroll
    for (int off = 32; off > 0; off >>= 1) {
        d0 += __shfl_down(d0, off, 64);
        d1 += __shfl_down(d1, off, 64);
    }
    __shared__ double sh[2][4];
    const int wid = threadIdx.x >> 6, lane = threadIdx.x & 63;
    if (lane == 0) { sh[0][wid] = d0; sh[1][wid] = d1; }
    __syncthreads();
    if (threadIdx.x == 0) {
        double t0s = 0, t1s = 0;
        #pragma unroll
        for (int w = 0; w < 4; ++w) { t0s += sh[0][w]; t1s += sh[1][w]; }
        ps[blockIdx.x * 2 + 0] = t0s;
        ps[blockIdx.x * 2 + 1] = t1s;
    }
}

// ---------------------------------------------------------------------------
// K4: THE single big pass — gae recompute (b16 + g_in) + value loss + action
// loss + entropy, all in one stream. Redundant preamble (round-2 proven
// pattern): each block reduces ps (16 KB, L2-resident) -> mu, invs.
// Block partials (vsum, asum, esum) -> pl (plain stores).
__global__ __launch_bounds__(256) void k_fused(
    const ushort4* __restrict__ b16,
    const float4* __restrict__ g_in4,
    const float4* __restrict__ vp4,
    const float4* __restrict__ nv4,
    const float4* __restrict__ lp4,
    const float4* __restrict__ plp4,
    const float4* __restrict__ ent4,
    const double* __restrict__ ps,
    double* __restrict__ pl)           // [PC_BLOCKS][3]
{
    __shared__ double sh[3][4];
    __shared__ double bc[2];
    const int tid = threadIdx.x;

    // --- redundant stats reduce (mu, invs) from ps ---
    {
        double s0 = 0.0, s1 = 0.0;
        for (int i = tid; i < PC_BLOCKS; i += 256) {
            s0 += ps[i * 2 + 0];
            s1 += ps[i * 2 + 1];
        }
        #pragma unroll
        for (int off = 32; off > 0; off >>= 1) {
            s0 += __shfl_down(s0, off, 64);
            s1 += __shfl_down(s1, off, 64);
        }
        const int wid = tid >> 6, lane = tid & 63;
        if (lane == 0) { sh[0][wid] = s0; sh[1][wid] = s1; }
        __syncthreads();
        if (tid == 0) {
            double sum = 0, sum2 = 0;
            #pragma unroll
            for (int w = 0; w < 4; ++w) { sum += sh[0][w]; sum2 += sh[1][w]; }
            const double M = (double)M_TOT;
            const double mu = sum / M;
            double var = (sum2 - sum * sum / M) / (M - 1.0);
            if (var < 0.0) var = 0.0;
            bc[0] = mu;
            bc[1] = 1.0 / (sqrt(var) + 1e-5);
        }
        __syncthreads();
    }
    const float mu   = (float)bc[0];
    const float invs = (float)bc[1];

    // --- single pass over this block's chunk ---
    const int g  = blockIdx.x * 256 + tid;
    const int j  = g & (NV4 - 1);
    const int c  = g >> 11;
    const int t0 = c * L_CHUNK;

    float4 gv = g_in4[c * NV4 + j];
    float v_s = 0.f, a_s = 0.f, e_s = 0.f;

    #pragma unroll
    for (int i = L_CHUNK - 1; i >= 0; --i) {
        const int idx = (t0 + i) * NV4 + j;
        const ushort4 h = b16[idx];
        const float4 V  = vp4[idx];
        const float4 Nv = nv4[idx];
        const float4 L  = lp4[idx];
        const float4 Pp = plp4[idx];
        const float4 E  = ent4[idx];
#define PFC(comp, HH) { \
        const unsigned short hh = (HH); \
        const float bf = bf2f(hh); \
        const float a  = (hh & 1u) ? kGLAM : 0.0f; \
        gv.comp = fmaf(a, gv.comp, bf); \
        const float qd = Nv.comp - V.comp; \
        const float e1 = qd - gv.comp; \
        const float e2 = fminf(fmaxf(qd, -0.2f), 0.2f) - gv.comp; \
        v_s += fmaxf(e1 * e1, e2 * e2); \
        const float x  = (gv.comp - mu) * invs; \
        const float rr = __expf(L.comp - Pp.comp); \
        const float rc = fminf(fmaxf(rr, 0.8f), 1.2f); \
        a_s += fminf(rr * x, rc * x); }
        PFC(x, h.x) PFC(y, h.y) PFC(z, h.z) PFC(w, h.w)
#undef PFC
        e_s += E.x + E.y + E.z + E.w;
    }

    double d0 = (double)v_s, d1 = (double)a_s, d2 = (double)e_s;
    #pragma unroll
    for (int off = 32; off > 0; off >>= 1) {
        d0 += __shfl_down(d0, off, 64);
        d1 += __shfl_down(d1, off, 64);
        d2 += __shfl_down(d2, off, 64);
    }
    const int wid = tid >> 6, lane = tid & 63;
    if (lane == 0) { sh[0][wid] = d0; sh[1][wid] = d1; sh[2][wid] = d2; }
    __syncthreads();
    if (tid == 0) {
        double t0s = 0, t1s = 0, t2s = 0;
        #pragma unroll
        for (int w = 0; w < 4; ++w) { t0s += sh[0][w]; t1s += sh[1][w]; t2s += sh[2][w]; }
        pl[blockIdx.x * 3 + 0] = t0s;
        pl[blockIdx.x * 3 + 1] = t1s;
        pl[blockIdx.x * 3 + 2] = t2s;
    }
}

// ---------------------------------------------------------------------------
// K5: reduce k_fused partials -> final scalar.
__global__ __launch_bounds__(256) void k_final(
    const double* __restrict__ pl, float* __restrict__ out)
{
    double s0 = 0.0, s1 = 0.0, s2 = 0.0;
    for (int i = threadIdx.x; i < PC_BLOCKS; i += 256) {
        s0 += pl[i * 3 + 0];
        s1 += pl[i * 3 + 1];
        s2 += pl[i * 3 + 2];
    }
    #pragma unroll
    for (int off = 32; off > 0; off >>= 1) {
        s0 += __shfl_down(s0, off, 64);
        s1 += __shfl_down(s1, off, 64);
        s2 += __shfl_down(s2, off, 64);
    }
    __shared__ double sh[3][4];
    const int wid = threadIdx.x >> 6, lane = threadIdx.x & 63;
    if (lane == 0) { sh[0][wid] = s0; sh[1][wid] = s1; sh[2][wid] = s2; }
    __syncthreads();
    if (threadIdx.x == 0) {
        double vsum = 0, asum = 0, esum = 0;
        #pragma unroll
        for (int w = 0; w < 4; ++w) { vsum += sh[0][w]; asum += sh[1][w]; esum += sh[2][w]; }
        const double M = (double)M_TOT;
        out[0] = (float)(0.25 * vsum / M - asum / M - 0.01 * esum / M);
    }
}

// ---------------------------------------------------------------------------
extern "C" void kernel_launch(void* const* d_in, const int* in_sizes, int n_in,
                              void* d_out, int out_size, void* d_ws, size_t ws_size,
                              hipStream_t stream) {
    const float* rewards     = (const float*)d_in[0];   // (T, N)
    const float* masks       = (const float*)d_in[1];   // (T+1, N)
    const float* bad_masks   = (const float*)d_in[2];   // (T+1, N)
    const float* value_preds = (const float*)d_in[3];   // (T+1, N)
    const float* last_value  = (const float*)d_in[4];   // (N,)
    const float* log_prob    = (const float*)d_in[5];   // (T, N)
    const float* prev_lp     = (const float*)d_in[6];   // (T, N)
    const float* new_value   = (const float*)d_in[7];   // (T, N)
    const float* dist_ent    = (const float*)d_in[8];   // (T, N)

    char* ws = (char*)d_ws;
    double* psb = (double*)(ws + 256);
    double* pl  = (double*)(ws + 32768);
    unsigned short* b16 = (unsigned short*)(ws + 65536);
    const size_t CM = (size_t)C_CHUNKS * N_DIM * 4;     // 4 MB per chunk-map array
    char* base = ws + 65536 + (size_t)M_TOT * 2;
    float* A = (float*)(base);
    float* B = (float*)(base + CM);
    float* P = (float*)(base + 2 * CM);
    float* Q = (float*)(base + 3 * CM);
    float* U = (float*)(base + 4 * CM);
    float* V = (float*)(base + 5 * CM);
    float* W = (float*)(base + 6 * CM);

    k_pc<<<PC_BLOCKS, 256, 0, stream>>>((const float4*)rewards,
                                        (const float4*)masks,
                                        (const float4*)bad_masks,
                                        (const float4*)value_preds,
                                        (const float4*)last_value,
                                        (ushort4*)b16,
                                        (float4*)A, (float4*)B,
                                        (float4*)P, (float4*)Q,
                                        (float4*)U, (float4*)V, (float4*)W);
    k_scan<<<SCAN_BLOCKS, 256, 0, stream>>>((float4*)A, (const float4*)B);
    k_cs<<<PC_BLOCKS, 256, 0, stream>>>((const float4*)A /* g_in */,
                                        (const float4*)P, (const float4*)Q,
                                        (const float4*)U, (const float4*)V,
                                        (const float4*)W, psb);
    k_fused<<<PC_BLOCKS, 256, 0, stream>>>((const ushort4*)b16,
                                           (const float4*)A /* g_in */,
                                           (const float4*)value_preds,
                                           (const float4*)new_value,
                                           (const float4*)log_prob,
                                           (const float4*)prev_lp,
                                           (const float4*)dist_ent, psb, pl);
    k_final<<<1, 256, 0, stream>>>(pl, (float*)d_out);
}